// Round 1
// baseline (1786.414 us; speedup 1.0000x reference)
//
#include <hip/hip_runtime.h>

#define T_LEN 4096

__device__ __forceinline__ float frcp(float x) { return __builtin_amdgcn_rcpf(x); }

__device__ __forceinline__ float silu_f(float x) {
  // x * sigmoid(x); robust at +-inf (exp->inf => rcp->0 => 0; exp->0 => x)
  return x * frcp(1.0f + __expf(-x));
}

__device__ __forceinline__ float tanh_f(float x) {
  // 1 - 2/(1+exp(2x)); robust: x->+inf => 1, x->-inf => -1
  return 1.0f - 2.0f * frcp(1.0f + __expf(2.0f * x));
}

// One wave (64 lanes) per batch element. All cross-lane comm is intra-wave.
// Lane l roles:
//   z-dot  : row h16 = l&15 of (p ? cW1 : vW1), p = (l>>4)&1  (lanes 32..63 duplicate)
//   f-dot  : row hf = l>>2 of vW2 (each row duplicated on 4 lanes)
//   g-dots : rows 2l, 2l+1 of cW2  => g[hf][d0], g[hf][d0+1] with d0 = (2l)&7
//   update : quad {4*hf..4*hf+3} reduces the einsum partials via shfl_xor
__global__ __launch_bounds__(64) void disc_kernel(
    const float* __restrict__ ts, const float* __restrict__ ys,
    const float* __restrict__ iW1, const float* __restrict__ ib1,
    const float* __restrict__ iW2, const float* __restrict__ ib2,
    const float* __restrict__ vW1, const float* __restrict__ vb1,
    const float* __restrict__ vW2, const float* __restrict__ vb2,
    const float* __restrict__ cW1, const float* __restrict__ cb1,
    const float* __restrict__ cW2, const float* __restrict__ cb2,
    const float* __restrict__ rW, const float* __restrict__ rb,
    float* __restrict__ out)
{
  const int b   = blockIdx.x;
  const int l   = threadIdx.x;
  const int h16 = l & 15;
  const int p   = (l >> 4) & 1;
  const int hf  = l >> 2;
  const int d0  = (2 * l) & 7;

  __shared__ __align__(16) float sbuf[32];   // [s1(16) | s2(16)]
  __shared__ __align__(16) float ybuf[16];   // replicated state
  __shared__ __align__(16) float xbuf[256];  // 32 staged ys rows (8 floats each)

  const float* __restrict__ ysb = ys + (size_t)b * (T_LEN * 8);

  // ---- per-lane weight registers (lipswish 0.909 folded into W2 / cW2) ----
  float W1r[17], b1;
  {
    const float* W1 = p ? cW1 : vW1;
    const float* bv = p ? cb1 : vb1;
#pragma unroll
    for (int k = 0; k < 17; ++k) W1r[k] = W1[h16 * 17 + k];
    b1 = bv[h16];
  }
  float W2r[16];
#pragma unroll
  for (int k = 0; k < 16; ++k) W2r[k] = 0.909f * vW2[hf * 16 + k];
  const float b2 = vb2[hf];

  float G0[16], G1[16];
#pragma unroll
  for (int k = 0; k < 16; ++k) {
    G0[k] = 0.909f * cW2[(2 * l) * 16 + k];
    G1[k] = 0.909f * cW2[(2 * l + 1) * 16 + k];
  }
  const float bg0 = cb2[2 * l];
  const float bg1 = cb2[2 * l + 1];

  const float t0 = ts[0];

  // ---- initial hidden state: y0 = iMLP([t0, ys[b,0,:]]) ----
  float y[16];
  {
    float acc = ib1[h16] + iW1[h16 * 9] * t0;
#pragma unroll
    for (int d = 0; d < 8; ++d) acc = fmaf(iW1[h16 * 9 + 1 + d], ysb[d], acc);
    acc = fmaxf(acc, 0.0f);            // relu hidden
    sbuf[h16] = acc;                   // duplicate lanes write identical values
    __syncthreads();
    float acc2 = ib2[h16];
#pragma unroll
    for (int k = 0; k < 16; ++k) acc2 = fmaf(iW2[h16 * 16 + k], sbuf[k], acc2);
    ybuf[h16] = acc2;
    __syncthreads();
#pragma unroll
    for (int k = 0; k < 16; ++k) y[k] = ybuf[k];
  }

  // ---- readout at t0 ----
  {
    float o = rb[0];
#pragma unroll
    for (int k = 0; k < 16; ++k) o = fmaf(rW[k], y[k], o);
    if (l == 0) out[2 * b] = o;
  }

  // previous-row values for this lane's two dx components
  float a0 = ysb[d0];
  float a1 = ysb[d0 + 1];

  for (int chunk = 0; chunk < 128; ++chunk) {
    const int base = chunk * 32;
    {
      // stage rows base+1 .. base+32 (256 floats) into LDS
      int elem = (base + 1) * 8 + l * 4;
      elem = min(elem, T_LEN * 8 - 4);   // clamp: tail rows never read
      const float4 xq = *(const float4*)(ysb + elem);
      *(float4*)(xbuf + l * 4) = xq;
    }
    const int nsteps = min(32, (T_LEN - 1) - base);
    for (int j = 0; j < nsteps; ++j) {
      const float t = t0 + (float)(base + j);
      // u = W1row . [t, y] + b1   (two chains for FMA-latency overlap)
      float ua = fmaf(W1r[0], t, b1);
      float ub = 0.0f;
#pragma unroll
      for (int k = 0; k < 8; ++k) {
        ua = fmaf(W1r[1 + k], y[k], ua);
        ub = fmaf(W1r[9 + k], y[8 + k], ub);
      }
      const float s = silu_f(ua + ub);
      sbuf[l & 31] = s;                 // lanes 32..63 dup-write identical values
      __syncthreads();

      float sv[32];
      {
        const float4* sb4 = (const float4*)sbuf;
#pragma unroll
        for (int k = 0; k < 8; ++k) {
          const float4 q = sb4[k];
          sv[4 * k + 0] = q.x; sv[4 * k + 1] = q.y;
          sv[4 * k + 2] = q.z; sv[4 * k + 3] = q.w;
        }
      }
      // three interleaved dot chains: f (vW2 row hf), g rows 2l, 2l+1
      float fa = b2, ga = bg0, gb = bg1;
#pragma unroll
      for (int k = 0; k < 16; ++k) {
        fa = fmaf(W2r[k], sv[k], fa);
        ga = fmaf(G0[k], sv[16 + k], ga);
        gb = fmaf(G1[k], sv[16 + k], gb);
      }
      fa = tanh_f(fa);
      ga = tanh_f(ga);
      gb = tanh_f(gb);

      // einsum partial: this lane's two d-components of g[hf,:] . dx
      const float2 bx = *(const float2*)(xbuf + j * 8 + d0);
      float pr = fmaf(ga, bx.x - a0, gb * (bx.y - a1));
      a0 = bx.x; a1 = bx.y;
      pr += __shfl_xor(pr, 1);
      pr += __shfl_xor(pr, 2);          // full sum over d in all 4 quad lanes

      const float ynew = ybuf[hf] + fa + pr;  // quad lanes produce identical value
      ybuf[hf] = ynew;
      __syncthreads();
#pragma unroll
      for (int k = 0; k < 16; ++k) y[k] = ybuf[k];
    }
  }

  // ---- readout at t1 ----
  {
    float o = rb[0];
#pragma unroll
    for (int k = 0; k < 16; ++k) o = fmaf(rW[k], y[k], o);
    if (l == 0) out[2 * b + 1] = o;
  }
}

extern "C" void kernel_launch(void* const* d_in, const int* in_sizes, int n_in,
                              void* d_out, int out_size, void* d_ws, size_t ws_size,
                              hipStream_t stream) {
  (void)in_sizes; (void)n_in; (void)out_size; (void)d_ws; (void)ws_size;
  const float* ts  = (const float*)d_in[0];
  const float* ys  = (const float*)d_in[1];
  const float* iW1 = (const float*)d_in[2];
  const float* ib1 = (const float*)d_in[3];
  const float* iW2 = (const float*)d_in[4];
  const float* ib2 = (const float*)d_in[5];
  const float* vW1 = (const float*)d_in[6];
  const float* vb1 = (const float*)d_in[7];
  const float* vW2 = (const float*)d_in[8];
  const float* vb2 = (const float*)d_in[9];
  const float* cW1 = (const float*)d_in[10];
  const float* cb1 = (const float*)d_in[11];
  const float* cW2 = (const float*)d_in[12];
  const float* cb2 = (const float*)d_in[13];
  const float* rW  = (const float*)d_in[14];
  const float* rb  = (const float*)d_in[15];
  float* out = (float*)d_out;
  hipLaunchKernelGGL(disc_kernel, dim3(512), dim3(64), 0, stream,
                     ts, ys, iW1, ib1, iW2, ib2, vW1, vb1, vW2, vb2,
                     cW1, cb1, cW2, cb2, rW, rb, out);
}

// Round 2
// 1307.880 us; speedup vs baseline: 1.3659x; 1.3659x over previous
//
#include <hip/hip_runtime.h>

#define T_LEN 4096

__device__ __forceinline__ float frcp(float x) { return __builtin_amdgcn_rcpf(x); }

__device__ __forceinline__ float silu_f(float x) {
  // x * sigmoid(x); robust at +-inf (exp->inf => rcp->0 => 0; exp->0 => x)
  return x * frcp(1.0f + __expf(-x));
}

__device__ __forceinline__ float tanh_f(float x) {
  // 1 - 2/(1+exp(2x)); robust: x->+inf => 1, x->-inf => -1
  return 1.0f - 2.0f * frcp(1.0f + __expf(2.0f * x));
}

__device__ __forceinline__ float rl(float v, int lane) {
  // wave-uniform read of lane's value -> SGPR (usable as scalar FMA operand)
  return __int_as_float(__builtin_amdgcn_readlane(__float_as_int(v), lane));
}

__device__ __forceinline__ float rfl(float v) {
  return __int_as_float(__builtin_amdgcn_readfirstlane(__float_as_int(v)));
}

// quad_perm DPP butterfly adds (VALU pipe, not DS): xor1 = [1,0,3,2] = 0xB1,
// xor2 = [2,3,0,1] = 0x4E
template <int CTRL>
__device__ __forceinline__ float dpp_add(float x) {
  int t = __builtin_amdgcn_mov_dpp(__float_as_int(x), CTRL, 0xF, 0xF, true);
  return x + __int_as_float(t);
}

// One wave (64 lanes) per batch element; block = 1 wave => NO barriers needed
// (same-wave DS ops are processed in order; compiler preserves may-alias order).
// Lane l roles:
//   z-dot  : row h16 = l&15 of (p ? cW1 : vW1), p=(l>>4)&1 -> s[l&31] (hi dup)
//   f-dot  : row hf = l>>2 of vW2 (dup x4), via SGPR-broadcast s
//   g-dots : rows 2l, 2l+1 of cW2 => g[hf][d0], g[hf][d0+1], d0 = (2l)&7
//   reduce : quad DPP butterfly sums einsum partials; lane keeps y[hf] (VGPR),
//            full y[0..15] lives in SGPRs via readlane(lane 4h).
__global__ __launch_bounds__(64) void disc_kernel(
    const float* __restrict__ ts, const float* __restrict__ ys,
    const float* __restrict__ iW1, const float* __restrict__ ib1,
    const float* __restrict__ iW2, const float* __restrict__ ib2,
    const float* __restrict__ vW1, const float* __restrict__ vb1,
    const float* __restrict__ vW2, const float* __restrict__ vb2,
    const float* __restrict__ cW1, const float* __restrict__ cb1,
    const float* __restrict__ cW2, const float* __restrict__ cb2,
    const float* __restrict__ rW, const float* __restrict__ rb,
    float* __restrict__ out)
{
  const int b   = blockIdx.x;
  const int l   = threadIdx.x;
  const int h16 = l & 15;
  const int p   = (l >> 4) & 1;
  const int hf  = l >> 2;
  const int d0  = (2 * l) & 7;

  __shared__ __align__(16) float sbuf[16];   // init-phase hidden
  __shared__ __align__(16) float ybuf[16];   // init-phase state
  __shared__ __align__(16) float xbuf[256];  // 32 staged ys rows (8 floats each)

  const float* __restrict__ ysb = ys + (size_t)b * (T_LEN * 8);

  // ---- per-lane weight registers (lipswish 0.909 folded into W2 / cW2) ----
  float W1r[17], b1;
  {
    const float* W1 = p ? cW1 : vW1;
    const float* bv = p ? cb1 : vb1;
#pragma unroll
    for (int k = 0; k < 17; ++k) W1r[k] = W1[h16 * 17 + k];
    b1 = bv[h16];
  }
  float W2r[16];
#pragma unroll
  for (int k = 0; k < 16; ++k) W2r[k] = 0.909f * vW2[hf * 16 + k];
  const float b2 = vb2[hf];

  float G0[16], G1[16];
#pragma unroll
  for (int k = 0; k < 16; ++k) {
    G0[k] = 0.909f * cW2[(2 * l) * 16 + k];
    G1[k] = 0.909f * cW2[(2 * l + 1) * 16 + k];
  }
  const float bg0 = cb2[2 * l];
  const float bg1 = cb2[2 * l + 1];

  const float t0 = ts[0];

  // ---- initial hidden state: y0 = iMLP([t0, ys[b,0,:]]) (cold path, via LDS)
  float y_own;            // this lane's y[hf] (VGPR, carried across steps)
  float yu[16];           // wave-uniform copy of y (SGPRs via readlane)
  {
    float acc = ib1[h16] + iW1[h16 * 9] * t0;
#pragma unroll
    for (int d = 0; d < 8; ++d) acc = fmaf(iW1[h16 * 9 + 1 + d], ysb[d], acc);
    acc = fmaxf(acc, 0.0f);            // relu hidden
    sbuf[h16] = acc;                   // dup lanes write identical values
    float acc2 = ib2[h16];
#pragma unroll
    for (int k = 0; k < 16; ++k) acc2 = fmaf(iW2[h16 * 16 + k], sbuf[k], acc2);
    ybuf[h16] = acc2;
    y_own = ybuf[hf];
#pragma unroll
    for (int k = 0; k < 16; ++k) yu[k] = rfl(ybuf[k]);
  }

  // ---- readout at t0 ----
  {
    float o = rb[0];
#pragma unroll
    for (int k = 0; k < 16; ++k) o = fmaf(rW[k], yu[k], o);
    if (l == 0) out[2 * b] = o;
  }

  // previous-row values for this lane's two dx components
  float a0 = ysb[d0];
  float a1 = ysb[d0 + 1];

  float t = t0;
  for (int chunk = 0; chunk < 128; ++chunk) {
    const int base = chunk * 32;
    {
      // stage rows base+1 .. base+32 (256 floats) into LDS
      int elem = (base + 1) * 8 + l * 4;
      elem = min(elem, T_LEN * 8 - 4);   // clamp: tail rows never read
      const float4 xq = *(const float4*)(ysb + elem);
      *(float4*)(xbuf + l * 4) = xq;
    }
    const int nsteps = min(32, (T_LEN - 1) - base);
    for (int j = 0; j < nsteps; ++j) {
      // dx read first: ds_read latency hides under zdot/silu/dots
      const float2 bx = *(const float2*)(xbuf + j * 8 + d0);

      // u = W1row . [t, y] + b1   (two chains for FMA-latency overlap)
      float ua = fmaf(W1r[0], t, b1);
      float ub = 0.0f;
#pragma unroll
      for (int k = 0; k < 8; ++k) {
        ua = fmaf(W1r[1 + k], yu[k], ua);
        ub = fmaf(W1r[9 + k], yu[8 + k], ub);
      }
      const float s = silu_f(ua + ub);

      // broadcast all 32 s-values to SGPRs (lane k owns s[k])
      float su[32];
#pragma unroll
      for (int k = 0; k < 32; ++k) su[k] = rl(s, k);

      // six accumulator chains (2 per output) to cut FMA-latency serialization
      float fa = b2,  fb = 0.0f;
      float ga = bg0, gc = 0.0f;
      float gb = bg1, gd = 0.0f;
#pragma unroll
      for (int k = 0; k < 8; ++k) {
        fa = fmaf(W2r[k],     su[k],      fa);
        fb = fmaf(W2r[8 + k], su[8 + k],  fb);
        ga = fmaf(G0[k],      su[16 + k], ga);
        gc = fmaf(G0[8 + k],  su[24 + k], gc);
        gb = fmaf(G1[k],      su[16 + k], gb);
        gd = fmaf(G1[8 + k],  su[24 + k], gd);
      }
      const float fv = tanh_f(fa + fb);
      const float g0 = tanh_f(ga + gc);
      const float g1 = tanh_f(gb + gd);

      // einsum partial: this lane's two d-components of g[hf,:] . dx
      float pr = fmaf(g0, bx.x - a0, g1 * (bx.y - a1));
      a0 = bx.x; a1 = bx.y;
      pr = dpp_add<0xB1>(pr);   // + lane^1
      pr = dpp_add<0x4E>(pr);   // + lane^2  -> full d-sum in all 4 quad lanes

      y_own = y_own + fv + pr;  // quad lanes hold identical y[hf]
#pragma unroll
      for (int h = 0; h < 16; ++h) yu[h] = rl(y_own, 4 * h);

      t += 1.0f;
    }
  }

  // ---- readout at t1 ----
  {
    float o = rb[0];
#pragma unroll
    for (int k = 0; k < 16; ++k) o = fmaf(rW[k], yu[k], o);
    if (l == 0) out[2 * b + 1] = o;
  }
}

extern "C" void kernel_launch(void* const* d_in, const int* in_sizes, int n_in,
                              void* d_out, int out_size, void* d_ws, size_t ws_size,
                              hipStream_t stream) {
  (void)in_sizes; (void)n_in; (void)out_size; (void)d_ws; (void)ws_size;
  const float* ts  = (const float*)d_in[0];
  const float* ys  = (const float*)d_in[1];
  const float* iW1 = (const float*)d_in[2];
  const float* ib1 = (const float*)d_in[3];
  const float* iW2 = (const float*)d_in[4];
  const float* ib2 = (const float*)d_in[5];
  const float* vW1 = (const float*)d_in[6];
  const float* vb1 = (const float*)d_in[7];
  const float* vW2 = (const float*)d_in[8];
  const float* vb2 = (const float*)d_in[9];
  const float* cW1 = (const float*)d_in[10];
  const float* cb1 = (const float*)d_in[11];
  const float* cW2 = (const float*)d_in[12];
  const float* cb2 = (const float*)d_in[13];
  const float* rW  = (const float*)d_in[14];
  const float* rb  = (const float*)d_in[15];
  float* out = (float*)d_out;
  hipLaunchKernelGGL(disc_kernel, dim3(512), dim3(64), 0, stream,
                     ts, ys, iW1, ib1, iW2, ib2, vW1, vb1, vW2, vb2,
                     cW1, cb1, cW2, cb2, rW, rb, out);
}

// Round 3
// 1219.826 us; speedup vs baseline: 1.4645x; 1.0722x over previous
//
#include <hip/hip_runtime.h>

#define T_LEN 4096

typedef float v2f __attribute__((ext_vector_type(2)));

__device__ __forceinline__ float frcp(float x) { return __builtin_amdgcn_rcpf(x); }
__device__ __forceinline__ float fexp2(float x) { return __builtin_amdgcn_exp2f(x); }

__device__ __forceinline__ float rl(float v, int lane) {
  // wave-uniform read of lane's value -> SGPR (usable as scalar VALU operand)
  return __int_as_float(__builtin_amdgcn_readlane(__float_as_int(v), lane));
}
__device__ __forceinline__ float rfl(float v) {
  return __int_as_float(__builtin_amdgcn_readfirstlane(__float_as_int(v)));
}

// packed dual-FMA: acc = w*s + acc (VOP3P, full-rate fp32 pairs).
// s is a wave-uniform SGPR pair (the single allowed scalar operand).
__device__ __forceinline__ void pk_fma_s(v2f& acc, v2f w, v2f s) {
  asm("v_pk_fma_f32 %0, %1, %2, %0" : "+v"(acc) : "v"(w), "s"(s));
}

// quad_perm DPP butterfly adds: xor1 = 0xB1, xor2 = 0x4E
template <int CTRL>
__device__ __forceinline__ float dpp_add(float x) {
  int t = __builtin_amdgcn_mov_dpp(__float_as_int(x), CTRL, 0xF, 0xF, true);
  return x + __int_as_float(t);
}

// One wave (64 lanes) per batch element; block = 1 wave => no barriers.
// Lane l roles (unchanged from round 2):
//   z-dot  : row h16 = l&15 of (p ? cW1 : vW1), p=(l>>4)&1 -> s[l&31]
//   f-dot  : row hf = l>>2 of vW2 (dup x4)
//   g-dots : rows 2l, 2l+1 of cW2 => g[hf][d0], g[hf][d0+1], d0=(2l)&7
//   reduce : quad DPP butterfly; lane keeps y[hf]; y broadcast via readlane.
// exp2 folding: W1 scaled by -log2e (silu arg), W2/G scaled by 2*log2e*0.909,
// biases by the matching factor (no 0.909 on biases of layer-2 args).
__global__ __launch_bounds__(64) void disc_kernel(
    const float* __restrict__ ts, const float* __restrict__ ys,
    const float* __restrict__ iW1, const float* __restrict__ ib1,
    const float* __restrict__ iW2, const float* __restrict__ ib2,
    const float* __restrict__ vW1, const float* __restrict__ vb1,
    const float* __restrict__ vW2, const float* __restrict__ vb2,
    const float* __restrict__ cW1, const float* __restrict__ cb1,
    const float* __restrict__ cW2, const float* __restrict__ cb2,
    const float* __restrict__ rW, const float* __restrict__ rb,
    float* __restrict__ out)
{
  const int b   = blockIdx.x;
  const int l   = threadIdx.x;
  const int h16 = l & 15;
  const int p   = (l >> 4) & 1;
  const int hf  = l >> 2;
  const int d0  = (2 * l) & 7;

  __shared__ __align__(16) float sbuf[16];
  __shared__ __align__(16) float ybuf[16];
  __shared__ __align__(16) float xbuf[1024];  // 2 x 64 dx-rows (8 floats each)

  const float* __restrict__ ysb = ys + (size_t)b * (T_LEN * 8);

  const float NL2E = -1.4426950408889634f;           // -log2(e)
  const float TSW  = 2.0f * 1.4426950408889634f * 0.909f;  // weight scale (tanh arg)
  const float TSB  = 2.0f * 1.4426950408889634f;           // bias scale (tanh arg)
  const float NLN2 = -0.6931471805599453f;           // -ln 2

  // ---- per-lane weights (scaled) ----
  float w1t, b1m;
  v2f W1y2[8];
  {
    const float* W1 = p ? cW1 : vW1;
    const float* bv = p ? cb1 : vb1;
    w1t = NL2E * W1[h16 * 17];
    b1m = NL2E * bv[h16];
#pragma unroll
    for (int k = 0; k < 8; ++k) {
      v2f w; w.x = NL2E * W1[h16 * 17 + 1 + 2 * k];
             w.y = NL2E * W1[h16 * 17 + 2 + 2 * k];
      W1y2[k] = w;
    }
  }
  v2f W2p[8], G0p[8], G1p[8];
#pragma unroll
  for (int k = 0; k < 8; ++k) {
    v2f a; a.x = TSW * vW2[hf * 16 + 2 * k]; a.y = TSW * vW2[hf * 16 + 2 * k + 1];
    W2p[k] = a;
    v2f c0; c0.x = TSW * cW2[(2 * l) * 16 + 2 * k]; c0.y = TSW * cW2[(2 * l) * 16 + 2 * k + 1];
    G0p[k] = c0;
    v2f c1; c1.x = TSW * cW2[(2 * l + 1) * 16 + 2 * k]; c1.y = TSW * cW2[(2 * l + 1) * 16 + 2 * k + 1];
    G1p[k] = c1;
  }
  const float b2p  = TSB * vb2[hf];
  const float bg0p = TSB * cb2[2 * l];
  const float bg1p = TSB * cb2[2 * l + 1];

  const float t0 = ts[0];

  // ---- initial hidden state (cold path, via LDS; same-wave DS is ordered) ----
  float y_own;
  v2f yu2[8];   // wave-uniform y pairs in SGPRs
  {
    float acc = ib1[h16] + iW1[h16 * 9] * t0;
#pragma unroll
    for (int d = 0; d < 8; ++d) acc = fmaf(iW1[h16 * 9 + 1 + d], ysb[d], acc);
    acc = fmaxf(acc, 0.0f);
    sbuf[h16] = acc;
    float acc2 = ib2[h16];
#pragma unroll
    for (int k = 0; k < 16; ++k) acc2 = fmaf(iW2[h16 * 16 + k], sbuf[k], acc2);
    ybuf[h16] = acc2;
    y_own = ybuf[hf];
#pragma unroll
    for (int k = 0; k < 8; ++k) {
      v2f r; r.x = rfl(ybuf[2 * k]); r.y = rfl(ybuf[2 * k + 1]);
      yu2[k] = r;
    }
  }

  // ---- readout at t0 ----
  {
    float o = rb[0];
#pragma unroll
    for (int k = 0; k < 8; ++k) {
      o = fmaf(rW[2 * k], yu2[k].x, o);
      o = fmaf(rW[2 * k + 1], yu2[k].y, o);
    }
    if (l == 0) out[2 * b] = o;
  }

  // ---- dx staging: 64-row chunks, double-buffered, prefetch next chunk ----
  const int CLAMP = T_LEN * 8 - 4;
  float4 A, Bq, Cq, Dq;
  {
    const int f0 = l * 8;
    A  = *(const float4*)(ysb + min(f0,      CLAMP));
    Bq = *(const float4*)(ysb + min(f0 + 4,  CLAMP));
    Cq = *(const float4*)(ysb + min(f0 + 8,  CLAMP));
    Dq = *(const float4*)(ysb + min(f0 + 12, CLAMP));
    float4 e0, e1;
    e0.x = Cq.x - A.x;  e0.y = Cq.y - A.y;  e0.z = Cq.z - A.z;  e0.w = Cq.w - A.w;
    e1.x = Dq.x - Bq.x; e1.y = Dq.y - Bq.y; e1.z = Dq.z - Bq.z; e1.w = Dq.w - Bq.w;
    *(float4*)(xbuf + l * 8)     = e0;
    *(float4*)(xbuf + l * 8 + 4) = e1;
  }

  float t = t0;
  for (int c = 0; c < 64; ++c) {
    // prefetch chunk c+1 (clamped; last chunk re-reads itself, harmless)
    {
      const int cn = min(c + 1, 63);
      const int f0 = cn * 512 + l * 8;
      A  = *(const float4*)(ysb + min(f0,      CLAMP));
      Bq = *(const float4*)(ysb + min(f0 + 4,  CLAMP));
      Cq = *(const float4*)(ysb + min(f0 + 8,  CLAMP));
      Dq = *(const float4*)(ysb + min(f0 + 12, CLAMP));
    }
    const float* __restrict__ xb = xbuf + (c & 1) * 512;
    const int base = c * 64;
    const int nsteps = min(64, (T_LEN - 1) - base);
    for (int j = 0; j < nsteps; ++j) {
      // dx read first: ds_read latency hides under z-dot/silu
      const v2f dx = *(const v2f*)(xb + j * 8 + d0);

      // m = -log2e * (W1row . [t, y] + b1)   (packed pairs, yu2 in SGPRs)
      const float m_t = fmaf(w1t, t, b1m);
      v2f ma; ma.x = m_t; ma.y = 0.0f;
      v2f mb; mb.x = 0.0f; mb.y = 0.0f;
#pragma unroll
      for (int k = 0; k < 4; ++k) {
        pk_fma_s(ma, W1y2[k], yu2[k]);
        pk_fma_s(mb, W1y2[4 + k], yu2[4 + k]);
      }
      const v2f ms = ma + mb;
      const float m = ms.x + ms.y;
      // silu: u * sigmoid(u), u = -ln2 * m, exp(-u) = exp2(m)
      const float eM = fexp2(m);
      const float u  = m * NLN2;
      const float s  = u * frcp(1.0f + eM);

      // broadcast s -> SGPR pairs; g-side (s[16..31]) first (longest path)
      v2f su2[16];
#pragma unroll
      for (int k = 8; k < 16; ++k) {
        v2f r; r.x = rl(s, 2 * k); r.y = rl(s, 2 * k + 1);
        su2[k] = r;
      }
      v2f ga; ga.x = bg0p; ga.y = 0.0f;
      v2f gc; gc.x = 0.0f; gc.y = 0.0f;
      v2f gb; gb.x = bg1p; gb.y = 0.0f;
      v2f gd; gd.x = 0.0f; gd.y = 0.0f;
#pragma unroll
      for (int k = 0; k < 4; ++k) {
        pk_fma_s(ga, G0p[k],     su2[8 + k]);
        pk_fma_s(gc, G0p[4 + k], su2[12 + k]);
        pk_fma_s(gb, G1p[k],     su2[8 + k]);
        pk_fma_s(gd, G1p[4 + k], su2[12 + k]);
      }
#pragma unroll
      for (int k = 0; k < 8; ++k) {
        v2f r; r.x = rl(s, 2 * k); r.y = rl(s, 2 * k + 1);
        su2[k] = r;
      }
      v2f fa; fa.x = b2p; fa.y = 0.0f;
      v2f fb; fb.x = 0.0f; fb.y = 0.0f;
#pragma unroll
      for (int k = 0; k < 4; ++k) {
        pk_fma_s(fa, W2p[k],     su2[k]);
        pk_fma_s(fb, W2p[4 + k], su2[4 + k]);
      }

      // tanh(x) = 1 - 2/(1+exp2(x'))  with x' pre-scaled by 2*log2e
      const v2f gs0 = ga + gc;
      const v2f gs1 = gb + gd;
      const float g0v = fmaf(-2.0f, frcp(1.0f + fexp2(gs0.x + gs0.y)), 1.0f);
      const float g1v = fmaf(-2.0f, frcp(1.0f + fexp2(gs1.x + gs1.y)), 1.0f);
      const v2f fs = fa + fb;
      const float fv = fmaf(-2.0f, frcp(1.0f + fexp2(fs.x + fs.y)), 1.0f);

      // einsum partial + quad butterfly reduce over d
      float pr = fmaf(g0v, dx.x, g1v * dx.y);
      pr = dpp_add<0xB1>(pr);
      pr = dpp_add<0x4E>(pr);

      y_own = y_own + (fv + pr);
#pragma unroll
      for (int k = 0; k < 8; ++k) {
        v2f r; r.x = rl(y_own, 8 * k); r.y = rl(y_own, 8 * k + 4);
        yu2[k] = r;
      }
      t += 1.0f;
    }
    // write prefetched chunk into the other buffer (vmcnt drain is off the
    // step critical path: 64 steps of compute covered the load latency)
    float* xbn = xbuf + ((c + 1) & 1) * 512;
    float4 e0, e1;
    e0.x = Cq.x - A.x;  e0.y = Cq.y - A.y;  e0.z = Cq.z - A.z;  e0.w = Cq.w - A.w;
    e1.x = Dq.x - Bq.x; e1.y = Dq.y - Bq.y; e1.z = Dq.z - Bq.z; e1.w = Dq.w - Bq.w;
    *(float4*)(xbn + l * 8)     = e0;
    *(float4*)(xbn + l * 8 + 4) = e1;
  }

  // ---- readout at t1 ----
  {
    float o = rb[0];
#pragma unroll
    for (int k = 0; k < 8; ++k) {
      o = fmaf(rW[2 * k], yu2[k].x, o);
      o = fmaf(rW[2 * k + 1], yu2[k].y, o);
    }
    if (l == 0) out[2 * b + 1] = o;
  }
}

extern "C" void kernel_launch(void* const* d_in, const int* in_sizes, int n_in,
                              void* d_out, int out_size, void* d_ws, size_t ws_size,
                              hipStream_t stream) {
  (void)in_sizes; (void)n_in; (void)out_size; (void)d_ws; (void)ws_size;
  const float* ts  = (const float*)d_in[0];
  const float* ys  = (const float*)d_in[1];
  const float* iW1 = (const float*)d_in[2];
  const float* ib1 = (const float*)d_in[3];
  const float* iW2 = (const float*)d_in[4];
  const float* ib2 = (const float*)d_in[5];
  const float* vW1 = (const float*)d_in[6];
  const float* vb1 = (const float*)d_in[7];
  const float* vW2 = (const float*)d_in[8];
  const float* vb2 = (const float*)d_in[9];
  const float* cW1 = (const float*)d_in[10];
  const float* cb1 = (const float*)d_in[11];
  const float* cW2 = (const float*)d_in[12];
  const float* cb2 = (const float*)d_in[13];
  const float* rW  = (const float*)d_in[14];
  const float* rb  = (const float*)d_in[15];
  float* out = (float*)d_out;
  hipLaunchKernelGGL(disc_kernel, dim3(512), dim3(64), 0, stream,
                     ts, ys, iW1, ib1, iW2, ib2, vW1, vb1, vW2, vb2,
                     cW1, cb1, cW2, cb2, rW, rb, out);
}